// Round 1
// baseline (150.577 us; speedup 1.0000x reference)
//
#include <hip/hip_runtime.h>
#include <math.h>

// Match numpy reference numerics exactly: no FMA contraction anywhere.
// Matching decisions (argmax ties, ov<0.5 threshold) rest on bit-exact floats.
#pragma clang fp contract(off)

#define BB      256
#define PP      3249         // 19*19*9
#define NCLS    21
#define NOBJ    12
#define CELLS   361          // 19*19
#define THRESH_ 0.5f

// 4-float vector with 4-byte alignment: conf rows (84 B) are only dword-aligned;
// gfx950 supports unaligned global wide loads, so this emits dwordx4.
typedef float vf4 __attribute__((ext_vector_type(4), aligned(4)));

// d_out layout (float32): [0]=loss_l/N, [1]=loss_c/N,
// [2 .. 2+BB*CELLS) = conf_t_featuremap, [2+BB*CELLS .. 2+2*BB*CELLS) = have_centerloss

// ---------------------------------------------------------------------------
// K1: logsumexp over the 21 classes for every (b,p) — independent of matching,
// so it runs at full occupancy (3249 blocks x 256 threads) instead of inside
// the 16-wave per-batch block. FP op order identical to the fused original:
// lse = logf(sum(expf(x-m))) + m rounded to float, so the later
// ce = lse - conf[c] is bit-identical to the previous in-register version.
// ---------------------------------------------------------------------------
__global__ __launch_bounds__(256) void lse_kernel(
    const float* __restrict__ conf, float* __restrict__ lse_out)
{
    int idx = blockIdx.x * 256 + threadIdx.x;      // exactly BB*PP threads
    if (idx >= BB * PP) return;
    const float* cd = conf + (size_t)idx * NCLS;
    const vf4* cd4 = (const vf4*)cd;
    float rw[NCLS];
#pragma unroll
    for (int v = 0; v < 5; ++v) {
        vf4 q = cd4[v];
        rw[4*v+0] = q[0]; rw[4*v+1] = q[1]; rw[4*v+2] = q[2]; rw[4*v+3] = q[3];
    }
    rw[20] = cd[20];

    float m = rw[0];
#pragma unroll
    for (int k = 1; k < NCLS; ++k) m = fmaxf(m, rw[k]);
    float s = 0.0f;
#pragma unroll
    for (int k = 0; k < NCLS; ++k) s += expf(rw[k] - m);
    lse_out[idx] = logf(s) + m;
}

// ---------------------------------------------------------------------------
// Fused per-batch kernel: IoU matching + conf_t + smooth-L1 + CE-from-lse +
// exact radix-select mining + per-cell outputs. One block/batch, 1024 threads.
//   s_key: (ce_bits<<32)|(~p) — distinct keys, order == reference stable argsort
//   s_bov: pass1 best-overlap; reused in pass2 to hold TRUE CE per prior
// Key bits 16..31 are 0xFFFF for all p<3249 -> radix rounds d=24,16 skipped.
// Histogram updates are ballot-aggregated: CE values cluster (exponent byte
// 0x40), so round 0 would serialize ~2.3K same-address LDS atomics without it.
// ---------------------------------------------------------------------------
__global__ __launch_bounds__(1024) void fused_kernel(
    const float* __restrict__ loc, const float* __restrict__ conf,
    const float* __restrict__ priors, const float* __restrict__ targets,
    const float* __restrict__ lse_in,
    int* __restrict__ numpos, double* __restrict__ lossl,
    double* __restrict__ lossc, float* __restrict__ out)
{
    const int b = blockIdx.x, tid = threadIdx.x;
    const int lane = tid & 63, wid = tid >> 6;   // 16 waves

    __shared__ float s_tx1[NOBJ], s_ty1[NOBJ], s_tx2[NOBJ], s_ty2[NOBJ];
    __shared__ float s_area_t[NOBJ];
    __shared__ int   s_label[NOBJ];
    __shared__ float s_bov[PP];                 // pass1: best ov; pass2+: true CE
    __shared__ short s_bidx[PP];
    __shared__ int   s_bpi[NOBJ];
    __shared__ float s_wov[NOBJ][16];
    __shared__ int   s_widx[NOBJ][16];
    __shared__ unsigned long long s_key[PP];
    __shared__ unsigned char s_ct[PP];
    __shared__ unsigned char s_sel[PP];
    __shared__ int s_hist[2][256];              // double-buffered: clear overlaps pick
    __shared__ int s_chosen, s_knext, s_nneg;
    __shared__ double s_pl[16];
    __shared__ int    s_pn[16];
    __shared__ double s_pc[16];

    if (tid < NOBJ) {
        const float* t = targets + ((size_t)b * NOBJ + tid) * 5;
        float x1 = t[0], y1 = t[1], x2 = t[2], y2 = t[3];
        s_tx1[tid] = x1; s_ty1[tid] = y1; s_tx2[tid] = x2; s_ty2[tid] = y2;
        s_label[tid] = (int)t[4];
        s_area_t[tid] = (x2 - x1) * (y2 - y1);
    }
    __syncthreads();

    // ---- Phase 1: IoU; per-prior best truth (first-max); per-truth best prior.
    float l_bov[NOBJ];
    int   l_bidx[NOBJ];
#pragma unroll
    for (int j = 0; j < NOBJ; ++j) { l_bov[j] = -1.0f; l_bidx[j] = 0x7FFFFFFF; }

    for (int p = tid; p < PP; p += 1024) {
        float cx = priors[4*p+0], cy = priors[4*p+1], w = priors[4*p+2], h = priors[4*p+3];
        float px1 = cx - w / 2.0f, py1 = cy - h / 2.0f;
        float px2 = cx + w / 2.0f, py2 = cy + h / 2.0f;
        float area_p = (px2 - px1) * (py2 - py1);
        float bov = -1.0f; int bidx = 0;
#pragma unroll
        for (int j = 0; j < NOBJ; ++j) {
            float ltx = fmaxf(s_tx1[j], px1);
            float lty = fmaxf(s_ty1[j], py1);
            float rbx = fminf(s_tx2[j], px2);
            float rby = fminf(s_ty2[j], py2);
            float iw = fmaxf(rbx - ltx, 0.0f);
            float ih = fmaxf(rby - lty, 0.0f);
            float inter = iw * ih;
            float iou = inter / ((s_area_t[j] + area_p) - inter);
            if (iou > bov) { bov = iou; bidx = j; }              // first max over truths
            if (iou > l_bov[j]) { l_bov[j] = iou; l_bidx[j] = p; } // best prior for truth j
        }
        s_bov[p] = bov;
        s_bidx[p] = (short)bidx;
    }

    // Wave butterfly reduce per-truth (max, ties -> smaller idx; associative).
#pragma unroll
    for (int j = 0; j < NOBJ; ++j) {
        float ov = l_bov[j]; int ix = l_bidx[j];
#pragma unroll
        for (int off = 32; off > 0; off >>= 1) {
            float ov2 = __shfl_xor(ov, off);
            int   ix2 = __shfl_xor(ix, off);
            if (ov2 > ov || (ov2 == ov && ix2 < ix)) { ov = ov2; ix = ix2; }
        }
        if (lane == 0) { s_wov[j][wid] = ov; s_widx[j][wid] = ix; }
    }
    __syncthreads();
    if (tid < NOBJ) {
        float ov = s_wov[tid][0]; int ix = s_widx[tid][0];
#pragma unroll
        for (int w2 = 1; w2 < 16; ++w2) {
            float ov2 = s_wov[tid][w2]; int ix2 = s_widx[tid][w2];
            if (ov2 > ov || (ov2 == ov && ix2 < ix)) { ov = ov2; ix = ix2; }
        }
        s_bpi[tid] = ix;
    }
    __syncthreads();

    // ---- Phase 2: conf_t + smooth-L1 + CE (lse precomputed) + mining keys.
    int bpi[NOBJ];
#pragma unroll
    for (int j = 0; j < NOBJ; ++j) bpi[j] = s_bpi[j];   // registers, not 12 LDS reads/prior

    int my_pos = 0;
    double my_lossl = 0.0;
    const float* confb = conf + (size_t)b * PP * NCLS;
    const float* lseb  = lse_in + (size_t)b * PP;
    for (int p = tid; p < PP; p += 1024) {
        int jov = -1;
#pragma unroll
        for (int j = 0; j < NOBJ; ++j) if (bpi[j] == p) jov = j;  // last-wins on duplicates
        int idx; float ov;
        if (jov >= 0) { idx = jov; ov = 2.0f; }
        else          { idx = (int)s_bidx[p]; ov = s_bov[p]; }
        int c = (ov < THRESH_) ? 0 : (s_label[idx] + 1);
        s_ct[p] = (unsigned char)c;

        // ce = (logf(s)+m) - conf[c]: identical rounding to the in-register
        // original since the lse intermediate was a rounded float there too.
        float lse = lseb[p];
        float cdc = confb[(size_t)p * NCLS + c];
        float ce  = lse - cdc;

        float v = (c > 0) ? 0.0f : ce;          // mining value (positives compete as 0)
        s_key[p] = ((unsigned long long)__float_as_uint(v) << 32)
                 | (unsigned int)(0xFFFFFFFFu - (unsigned int)p);
        s_bov[p] = ce;                           // true CE (ov dead after read above)

        if (c > 0) {
            ++my_pos;
            float cx = priors[4*p+0], cy = priors[4*p+1], w = priors[4*p+2], h = priors[4*p+3];
            float m0 = s_tx1[idx], m1 = s_ty1[idx], m2 = s_tx2[idx], m3 = s_ty2[idx];
            float g0 = ((m0 + m2) / 2.0f - cx) / (0.1f * w);
            float g1 = ((m1 + m3) / 2.0f - cy) / (0.1f * h);
            float g2 = logf((m2 - m0) / w) / 0.2f;
            float g3 = logf((m3 - m1) / h) / 0.2f;
            const float* ld = loc + ((size_t)b * PP + p) * 4;
            float d0 = ld[0] - g0, d1 = ld[1] - g1, d2 = ld[2] - g2, d3 = ld[3] - g3;
            float a0 = fabsf(d0), a1 = fabsf(d1), a2 = fabsf(d2), a3 = fabsf(d3);
            my_lossl += (double)((a0 < 1.0f) ? 0.5f * d0 * d0 : a0 - 0.5f);
            my_lossl += (double)((a1 < 1.0f) ? 0.5f * d1 * d1 : a1 - 0.5f);
            my_lossl += (double)((a2 < 1.0f) ? 0.5f * d2 * d2 : a2 - 0.5f);
            my_lossl += (double)((a3 < 1.0f) ? 0.5f * d3 * d3 : a3 - 0.5f);
        }
    }
#pragma unroll
    for (int off = 32; off > 0; off >>= 1) {
        my_lossl += __shfl_down(my_lossl, off);
        my_pos   += __shfl_down(my_pos, off);
    }
    if (lane == 0) { s_pl[wid] = my_lossl; s_pn[wid] = my_pos; }
    if (tid < 512) ((int*)s_hist)[tid] = 0;        // clear both hist buffers
    __syncthreads();
    if (tid == 0) {
        double L = 0.0; int n = 0;
#pragma unroll
        for (int w2 = 0; w2 < 16; ++w2) { L += s_pl[w2]; n += s_pn[w2]; }
        lossl[b] = L; numpos[b] = n;
        s_nneg = min(3 * n, PP - 1);   // n >= 1 (forced matches)
    }
    __syncthreads();

    // ---- Phase 3: exact radix select, 6 effective rounds (d=24,16 skipped:
    // key bits 16..31 are 0xFFFF for every key since p < 3249).
    // Ballot-aggregated histogram: build the "same bin" lane mask from 8
    // ballots; the lowest lane of each group does ONE atomicAdd of popcount.
    const int ds[6] = {56, 48, 40, 32, 8, 0};
    unsigned long long prefix = 0ull, pmask = 0ull;
    int kk = s_nneg;
#pragma unroll
    for (int ri = 0; ri < 6; ++ri) {
        const int d = ds[ri];
        int* hist = s_hist[ri & 1];
        for (int i = tid; i < PP; i += 1024) {
            unsigned long long key = s_key[i];
            bool active = ((key & pmask) == prefix);
            unsigned bin = (unsigned)((key >> d) & 0xFF);
            unsigned long long mm = __ballot(active);
#pragma unroll
            for (int bit = 0; bit < 8; ++bit) {
                unsigned long long bb = __ballot(active && ((bin >> bit) & 1));
                mm &= ((bin >> bit) & 1) ? bb : ~bb;
            }
            if (active && (__ffsll((unsigned long long)mm) - 1 == lane))
                atomicAdd(&hist[bin], (int)__popcll(mm));
        }
        __syncthreads();
        if (tid < 64) {   // wave 0: bin where top-down cumulative crosses kk
            int h0 = hist[4*lane+0], h1 = hist[4*lane+1];
            int h2 = hist[4*lane+2], h3 = hist[4*lane+3];
            int ls = h0 + h1 + h2 + h3;
            int x = ls;                       // inclusive suffix sum over lanes
#pragma unroll
            for (int off = 1; off < 64; off <<= 1) {
                int y = __shfl_down(x, off);
                if (lane + off < 64) x += y;
            }
            int excl = x - ls;                // sum over lanes > lane
            int cb3 = excl;
            int cb2 = cb3 + h3;
            int cb1 = cb2 + h2;
            int cb0 = cb1 + h1;
            if (cb3 < kk && kk <= cb3 + h3) { s_chosen = 4*lane+3; s_knext = kk - cb3; }
            if (cb2 < kk && kk <= cb2 + h2) { s_chosen = 4*lane+2; s_knext = kk - cb2; }
            if (cb1 < kk && kk <= cb1 + h1) { s_chosen = 4*lane+1; s_knext = kk - cb1; }
            if (cb0 < kk && kk <= cb0 + h0) { s_chosen = 4*lane+0; s_knext = kk - cb0; }
        } else if (tid < 64 + 256) {
            // clear the buffer round ri+2 will scan into (used by round ri-1;
            // wave 0 is reading the OTHER buffer right now, so no conflict)
            s_hist[(ri + 1) & 1][tid - 64] = 0;
        }
        __syncthreads();
        prefix |= ((unsigned long long)(unsigned int)s_chosen) << d;
        pmask  |= 0xFFull << d;
        kk = s_knext;
        if (d == 32) { prefix |= 0xFFFF0000ull; pmask |= 0xFFFF0000ull; }
        // s_chosen/s_knext next written only after round ri+1's post-scan
        // barrier, which every thread passes after reading them here.
    }
    const unsigned long long kth = prefix;   // exact nneg-th largest key

    // ---- Phase 4: selection + loss_c (true CE lives in s_bov for all p).
    double my_c = 0.0;
    for (int p = tid; p < PP; p += 1024) {
        int c = s_ct[p];
        bool sel = (c > 0) || (s_key[p] >= kth);
        s_sel[p] = sel ? 1 : 0;
        if (sel) my_c += (double)s_bov[p];
    }
    __syncthreads();

    // ---- Phase 5: per-cell outputs.
    for (int cI = tid; cI < CELLS; cI += 1024) {
        int mc = 0, hv = 0;
#pragma unroll
        for (int a = 0; a < 9; ++a) {
            int p = cI * 9 + a;
            int cv = s_ct[p];
            mc = (cv > mc) ? cv : mc;
            hv |= s_sel[p];
        }
        out[2 + (size_t)b * CELLS + cI] = (float)mc;
        out[2 + (size_t)BB * CELLS + (size_t)b * CELLS + cI] = (float)hv;
    }

#pragma unroll
    for (int off = 32; off > 0; off >>= 1) my_c += __shfl_down(my_c, off);
    if (lane == 0) s_pc[wid] = my_c;
    __syncthreads();
    if (tid == 0) {
        double L = 0.0;
#pragma unroll
        for (int w2 = 0; w2 < 16; ++w2) L += s_pc[w2];
        lossc[b] = L;
    }
}

__global__ __launch_bounds__(256) void finalize_kernel(
    const int* __restrict__ numpos, const double* __restrict__ lossl,
    const double* __restrict__ lossc, float* __restrict__ out)
{
    __shared__ double s_l[256], s_c[256];
    __shared__ int s_n[256];
    int tid = threadIdx.x;
    s_n[tid] = numpos[tid];     // BB == 256 == blockDim
    s_l[tid] = lossl[tid];
    s_c[tid] = lossc[tid];
    __syncthreads();
    for (int s = 128; s > 0; s >>= 1) {
        if (tid < s) { s_n[tid] += s_n[tid + s]; s_l[tid] += s_l[tid + s]; s_c[tid] += s_c[tid + s]; }
        __syncthreads();
    }
    if (tid == 0) {
        double N = (double)s_n[0];
        out[0] = (float)(s_l[0] / N);
        out[1] = (float)(s_c[0] / N);
    }
}

extern "C" void kernel_launch(void* const* d_in, const int* in_sizes, int n_in,
                              void* d_out, int out_size, void* d_ws, size_t ws_size,
                              hipStream_t stream) {
    const float* loc     = (const float*)d_in[0];  // (B, P, 4)
    const float* conf    = (const float*)d_in[1];  // (B, P, 21)
    const float* priors  = (const float*)d_in[2];  // (P, 4)
    const float* targets = (const float*)d_in[3];  // (B, 12, 5)
    float* out = (float*)d_out;

    double* ws_lossl  = (double*)d_ws;             // BB doubles
    double* ws_lossc  = ws_lossl + BB;             // BB doubles
    int*    ws_numpos = (int*)(ws_lossc + BB);     // BB ints
    float*  ws_lse    = (float*)(ws_numpos + BB);  // BB*PP floats (~3.3 MB)

    // K1: full-occupancy LSE over all (b,p). BB*PP == 3249*256 exactly.
    hipLaunchKernelGGL(lse_kernel, dim3((BB * PP) / 256), dim3(256), 0, stream,
                       conf, ws_lse);
    hipLaunchKernelGGL(fused_kernel, dim3(BB), dim3(1024), 0, stream,
                       loc, conf, priors, targets, ws_lse,
                       ws_numpos, ws_lossl, ws_lossc, out);
    hipLaunchKernelGGL(finalize_kernel, dim3(1), dim3(256), 0, stream,
                       ws_numpos, ws_lossl, ws_lossc, out);
}

// Round 2
// 141.914 us; speedup vs baseline: 1.0610x; 1.0610x over previous
//
#include <hip/hip_runtime.h>
#include <math.h>

// Match numpy reference numerics exactly: no FMA contraction anywhere.
// Matching decisions (argmax ties, ov<0.5 threshold) rest on bit-exact floats.
#pragma clang fp contract(off)

#define BB      256
#define PP      3249         // 19*19*9
#define NCLS    21
#define NOBJ    12
#define CELLS   361          // 19*19
#define THRESH_ 0.5f
#define HB      4096         // radix histogram bins (12-bit digits)

// 4-float vector with 4-byte alignment: conf rows (84 B) are only dword-aligned;
// gfx950 supports unaligned global wide loads, so this emits dwordx4.
typedef float vf4 __attribute__((ext_vector_type(4), aligned(4)));

// d_out layout (float32): [0]=loss_l/N, [1]=loss_c/N,
// [2 .. 2+BB*CELLS) = conf_t_featuremap, [2+BB*CELLS .. 2+2*BB*CELLS) = have_centerloss

struct Row { vf4 a, b, c, d, e; float f; };

__device__ __forceinline__ Row load_row(const float* cd) {
    const vf4* q = (const vf4*)cd;
    Row r;
    r.a = q[0]; r.b = q[1]; r.c = q[2]; r.d = q[3]; r.e = q[4];
    r.f = cd[20];
    return r;
}

// lse identical to reference op order: m = max chain k=0..20; s = sum of
// expf(x-m) k=0..20; result logf(s)+m (rounded float -> later ce = lse-conf[c]
// is bit-identical to computing ce inline).
__device__ __forceinline__ float lse21(const Row& r) {
    float m = r.a[0];
    m = fmaxf(m, r.a[1]); m = fmaxf(m, r.a[2]); m = fmaxf(m, r.a[3]);
    m = fmaxf(m, r.b[0]); m = fmaxf(m, r.b[1]); m = fmaxf(m, r.b[2]); m = fmaxf(m, r.b[3]);
    m = fmaxf(m, r.c[0]); m = fmaxf(m, r.c[1]); m = fmaxf(m, r.c[2]); m = fmaxf(m, r.c[3]);
    m = fmaxf(m, r.d[0]); m = fmaxf(m, r.d[1]); m = fmaxf(m, r.d[2]); m = fmaxf(m, r.d[3]);
    m = fmaxf(m, r.e[0]); m = fmaxf(m, r.e[1]); m = fmaxf(m, r.e[2]); m = fmaxf(m, r.e[3]);
    m = fmaxf(m, r.f);
    float s = 0.0f;
    s += expf(r.a[0]-m); s += expf(r.a[1]-m); s += expf(r.a[2]-m); s += expf(r.a[3]-m);
    s += expf(r.b[0]-m); s += expf(r.b[1]-m); s += expf(r.b[2]-m); s += expf(r.b[3]-m);
    s += expf(r.c[0]-m); s += expf(r.c[1]-m); s += expf(r.c[2]-m); s += expf(r.c[3]-m);
    s += expf(r.d[0]-m); s += expf(r.d[1]-m); s += expf(r.d[2]-m); s += expf(r.d[3]-m);
    s += expf(r.e[0]-m); s += expf(r.e[1]-m); s += expf(r.e[2]-m); s += expf(r.e[3]-m);
    s += expf(r.f-m);
    return logf(s) + m;
}

// Ballot-aggregated histogram scan over PP 32-bit keys: CE values cluster in a
// few exponent bins, so per-key atomics would serialize; the 8-12 ballots build
// the equal-bin lane mask and the group leader does one atomicAdd of popcount.
template <int NBITS>
__device__ __forceinline__ void scan_hist(const unsigned* key_arr, int* hist,
                                          unsigned prefix, unsigned pmask,
                                          int shift, int tid, int lane) {
    for (int i = tid; i < PP; i += 1024) {
        unsigned key = key_arr[i];
        bool active = ((key & pmask) == prefix);
        unsigned bin = (key >> shift) & ((1u << NBITS) - 1u);
        unsigned long long mm = __ballot(active);
#pragma unroll
        for (int bit = 0; bit < NBITS; ++bit) {
            unsigned long long bb = __ballot(active && ((bin >> bit) & 1));
            mm &= ((bin >> bit) & 1) ? bb : ~bb;
        }
        if (active && (__ffsll((unsigned long long)mm) - 1 == lane))
            atomicAdd(&hist[bin], (int)__popcll(mm));
    }
}

// Wave-0 pick: find the bin where the top-down cumulative count crosses kv.
// Lane l owns bins [l*per, (l+1)*per); butterfly inclusive suffix-sum over
// lanes gives the higher-lane total, then a high->low walk within the lane.
__device__ __forceinline__ void pick_bin(const int* hist, int nbins, int kv, int lane,
                                         int* s_chosen, int* s_knext, int* s_cnt) {
    const int per = nbins >> 6;
    const int base = lane * per;
    int ls = 0;
    for (int k = 0; k < per; ++k) ls += hist[base + k];
    int x = ls;
#pragma unroll
    for (int off = 1; off < 64; off <<= 1) {
        int y = __shfl_down(x, off);
        if (lane + off < 64) x += y;
    }
    int cum = x - ls;                       // strictly-higher-lane total
    for (int k = per - 1; k >= 0; --k) {
        int h = hist[base + k];
        if (cum < kv && kv <= cum + h) { *s_chosen = base + k; *s_knext = kv - cum; *s_cnt = h; }
        cum += h;
    }
}

// ---------------------------------------------------------------------------
// Fused per-batch kernel. One block/batch, 1024 threads (16 waves, 1 block/CU).
// Phases: [0+1] conf-LSE stream + IoU matching (no barrier between; pipelined
// loads) -> per-truth reduce -> [2] conf_t + CE + smooth-L1 + 32-bit mining
// keys -> [3] 2-3-round radix select on value-only keys, exact tie path on
// index (rare) -> [4+5] one per-cell pass: sel, loss_c, featuremap outputs.
// ---------------------------------------------------------------------------
__global__ __launch_bounds__(1024, 4) void fused_kernel(
    const float* __restrict__ loc, const float* __restrict__ conf,
    const float* __restrict__ priors, const float* __restrict__ targets,
    int* __restrict__ numpos, double* __restrict__ lossl,
    double* __restrict__ lossc, float* __restrict__ out)
{
    const int b = blockIdx.x, tid = threadIdx.x;
    const int lane = tid & 63, wid = tid >> 6;   // 16 waves

    __shared__ float s_tx1[NOBJ], s_ty1[NOBJ], s_tx2[NOBJ], s_ty2[NOBJ];
    __shared__ float s_area_t[NOBJ];
    __shared__ int   s_label[NOBJ];
    __shared__ float s_bov[PP];                 // phase1: best ov; phase2+: true CE
    __shared__ short s_bidx[PP];
    __shared__ float s_lse[PP];                 // logsumexp per prior
    __shared__ float s_c0[PP];                  // conf[p][0] (common-case CE gather)
    __shared__ unsigned s_key[PP];              // mining value bits (v>=0 floats)
    __shared__ unsigned char s_ct[PP];
    __shared__ int   s_bpi[NOBJ];
    __shared__ float s_wov[NOBJ][16];
    __shared__ int   s_widx[NOBJ][16];
    __shared__ int s_hist[2][HB];               // double-buffered 12-bit histograms
    __shared__ int s_chosen, s_knext, s_cnt, s_nneg;
    __shared__ unsigned s_f;
    __shared__ double s_pl[16];
    __shared__ int    s_pn[16];
    __shared__ double s_pc[16];

    if (tid < NOBJ) {
        const float* t = targets + ((size_t)b * NOBJ + tid) * 5;
        float x1 = t[0], y1 = t[1], x2 = t[2], y2 = t[3];
        s_tx1[tid] = x1; s_ty1[tid] = y1; s_tx2[tid] = x2; s_ty2[tid] = y2;
        s_label[tid] = (int)t[4];
        s_area_t[tid] = (x2 - x1) * (y2 - y1);
    }
    __syncthreads();                                               // B1

    const float* confb = conf + (size_t)b * PP * NCLS;
    const int p0 = tid, p1 = tid + 1024, p2 = tid + 2048, p3 = tid + 3072;
    const bool h3 = (p3 < PP);                  // only tid<177 has a 4th prior

    // ---- Phase 1 prefetch: all prior rows + first conf row in flight.
    vf4 pr0 = *(const vf4*)(priors + 4 * p0);
    vf4 pr1 = *(const vf4*)(priors + 4 * p1);
    vf4 pr2 = *(const vf4*)(priors + 4 * p2);
    vf4 pr3; if (h3) pr3 = *(const vf4*)(priors + 4 * p3);
    Row ra = load_row(confb + (size_t)p0 * NCLS);   // latency hides under IoU

    // ---- Phase 1: IoU; per-prior best truth (first-max); per-truth best prior.
    float l_bov[NOBJ];
    int   l_bidx[NOBJ];
#pragma unroll
    for (int j = 0; j < NOBJ; ++j) { l_bov[j] = -1.0f; l_bidx[j] = 0x7FFFFFFF; }

    auto iou_body = [&](vf4 prr, int p) {
        float cx = prr[0], cy = prr[1], w = prr[2], h = prr[3];
        float px1 = cx - w / 2.0f, py1 = cy - h / 2.0f;
        float px2 = cx + w / 2.0f, py2 = cy + h / 2.0f;
        float area_p = (px2 - px1) * (py2 - py1);
        float bov = -1.0f; int bidx = 0;
#pragma unroll
        for (int j = 0; j < NOBJ; ++j) {
            float ltx = fmaxf(s_tx1[j], px1);
            float lty = fmaxf(s_ty1[j], py1);
            float rbx = fminf(s_tx2[j], px2);
            float rby = fminf(s_ty2[j], py2);
            float iw = fmaxf(rbx - ltx, 0.0f);
            float ih = fmaxf(rby - lty, 0.0f);
            float inter = iw * ih;
            float iou = inter / ((s_area_t[j] + area_p) - inter);
            if (iou > bov) { bov = iou; bidx = j; }                // first max over truths
            if (iou > l_bov[j]) { l_bov[j] = iou; l_bidx[j] = p; } // best prior for truth j
        }
        s_bov[p] = bov;
        s_bidx[p] = (short)bidx;
    };
    iou_body(pr0, p0);
    iou_body(pr1, p1);
    iou_body(pr2, p2);
    if (h3) iou_body(pr3, p3);

    // Wave butterfly reduce per-truth (max, ties -> smaller idx; associative).
#pragma unroll
    for (int j = 0; j < NOBJ; ++j) {
        float ov = l_bov[j]; int ix = l_bidx[j];
#pragma unroll
        for (int off = 32; off > 0; off >>= 1) {
            float ov2 = __shfl_xor(ov, off);
            int   ix2 = __shfl_xor(ix, off);
            if (ov2 > ov || (ov2 == ov && ix2 < ix)) { ov = ov2; ix = ix2; }
        }
        if (lane == 0) { s_wov[j][wid] = ov; s_widx[j][wid] = ix; }
    }

    // ---- Phase 0: conf-row LSE, ping-pong pipelined (load k+1 while exp-ing k).
    {
        Row rb = load_row(confb + (size_t)p1 * NCLS);
        s_lse[p0] = lse21(ra); s_c0[p0] = ra.a[0];
        Row rc = load_row(confb + (size_t)p2 * NCLS);
        s_lse[p1] = lse21(rb); s_c0[p1] = rb.a[0];
        Row rd; if (h3) rd = load_row(confb + (size_t)p3 * NCLS);
        s_lse[p2] = lse21(rc); s_c0[p2] = rc.a[0];
        if (h3) { s_lse[p3] = lse21(rd); s_c0[p3] = rd.a[0]; }
    }
    __syncthreads();                                               // B2

    if (tid < NOBJ) {
        float ov = s_wov[tid][0]; int ix = s_widx[tid][0];
#pragma unroll
        for (int w2 = 1; w2 < 16; ++w2) {
            float ov2 = s_wov[tid][w2]; int ix2 = s_widx[tid][w2];
            if (ov2 > ov || (ov2 == ov && ix2 < ix)) { ov = ov2; ix = ix2; }
        }
        s_bpi[tid] = ix;
    }
    __syncthreads();                                               // B3

    // ---- Phase 2: conf_t + CE (from s_lse/s_c0) + smooth-L1 + mining keys.
    int bpi[NOBJ];
#pragma unroll
    for (int j = 0; j < NOBJ; ++j) bpi[j] = s_bpi[j];

    int my_pos = 0;
    double my_lossl = 0.0;
    for (int p = tid; p < PP; p += 1024) {
        int jov = -1;
#pragma unroll
        for (int j = 0; j < NOBJ; ++j) if (bpi[j] == p) jov = j;  // last-wins on duplicates
        int idx; float ov;
        if (jov >= 0) { idx = jov; ov = 2.0f; }
        else          { idx = (int)s_bidx[p]; ov = s_bov[p]; }
        int c = (ov < THRESH_) ? 0 : (s_label[idx] + 1);
        s_ct[p] = (unsigned char)c;

        // ce = lse - conf[p][c]: c==0 served from LDS (common), else L2-warm gather.
        float lse = s_lse[p];
        float cdc = (c == 0) ? s_c0[p] : confb[(size_t)p * NCLS + c];
        float ce  = lse - cdc;

        float v = (c > 0) ? 0.0f : ce;          // mining value (positives compete as 0)
        s_key[p] = __float_as_uint(v);          // v >= 0 -> uint order == float order
        s_bov[p] = ce;                           // true CE (ov dead after read above)

        if (c > 0) {
            ++my_pos;
            float cx = priors[4*p+0], cy = priors[4*p+1], w = priors[4*p+2], h = priors[4*p+3];
            float m0 = s_tx1[idx], m1 = s_ty1[idx], m2 = s_tx2[idx], m3 = s_ty2[idx];
            float g0 = ((m0 + m2) / 2.0f - cx) / (0.1f * w);
            float g1 = ((m1 + m3) / 2.0f - cy) / (0.1f * h);
            float g2 = logf((m2 - m0) / w) / 0.2f;
            float g3 = logf((m3 - m1) / h) / 0.2f;
            const float* ld = loc + ((size_t)b * PP + p) * 4;
            float d0 = ld[0] - g0, d1 = ld[1] - g1, d2 = ld[2] - g2, d3 = ld[3] - g3;
            float a0 = fabsf(d0), a1 = fabsf(d1), a2 = fabsf(d2), a3 = fabsf(d3);
            my_lossl += (double)((a0 < 1.0f) ? 0.5f * d0 * d0 : a0 - 0.5f);
            my_lossl += (double)((a1 < 1.0f) ? 0.5f * d1 * d1 : a1 - 0.5f);
            my_lossl += (double)((a2 < 1.0f) ? 0.5f * d2 * d2 : a2 - 0.5f);
            my_lossl += (double)((a3 < 1.0f) ? 0.5f * d3 * d3 : a3 - 0.5f);
        }
    }
#pragma unroll
    for (int off = 32; off > 0; off >>= 1) {
        my_lossl += __shfl_down(my_lossl, off);
        my_pos   += __shfl_down(my_pos, off);
    }
    if (lane == 0) { s_pl[wid] = my_lossl; s_pn[wid] = my_pos; }
    for (int k = tid; k < 2 * HB; k += 1024) ((int*)s_hist)[k] = 0;  // clear both bufs
    __syncthreads();                                               // B4

    // ---- Phase 3: exact radix select on 32-bit value keys.
    // Digits 12/12/8 bits. Early exit when the crossing bin holds exactly one
    // key (common by round 1-2: CE floats are distinct); the full key is then
    // found with one lookup pass. True value-ties (kk<cnt after all 32 bits)
    // get one extra 12-bit round over descending index (4095-p), yielding the
    // exact index threshold. Selection set == old 64-bit (v,~p) key >= kth.
    unsigned prefix = 0u, pmask = 0u, fstar = 0u;
    int ptie = 0x7FFFFFFF;
    bool resolved = false;

    // Round 0 (bits 31..20). tid 0 folds the phase-2 reductions while others scan.
    if (tid == 0) {
        double L = 0.0; int n = 0;
#pragma unroll
        for (int w2 = 0; w2 < 16; ++w2) { L += s_pl[w2]; n += s_pn[w2]; }
        lossl[b] = L; numpos[b] = n;
        s_nneg = min(3 * n, PP - 1);   // n >= 1 (forced matches)
    }
    scan_hist<12>(s_key, s_hist[0], 0u, 0u, 20, tid, lane);
    __syncthreads();                                               // B5
    if (tid < 64) pick_bin(s_hist[0], HB, s_nneg, lane, &s_chosen, &s_knext, &s_cnt);
    else { for (int k = tid - 64; k < HB; k += 960) s_hist[1][k] = 0; }
    __syncthreads();                                               // B6
    prefix = ((unsigned)s_chosen) << 20; pmask = 0xFFF00000u;
    if (s_cnt == 1) {
        for (int i = tid; i < PP; i += 1024) {
            unsigned key = s_key[i];
            if ((key & pmask) == prefix) s_f = key;   // unique writer
        }
        __syncthreads();
        fstar = s_f; resolved = true;
    }

    // Round 1 (bits 19..8).
    if (!resolved) {
        scan_hist<12>(s_key, s_hist[1], prefix, pmask, 8, tid, lane);
        __syncthreads();
        if (tid < 64) pick_bin(s_hist[1], HB, s_knext, lane, &s_chosen, &s_knext, &s_cnt);
        else { for (int k = tid - 64; k < HB; k += 960) s_hist[0][k] = 0; }
        __syncthreads();
        prefix |= ((unsigned)s_chosen) << 8; pmask |= 0x000FFF00u;
        if (s_cnt == 1) {
            for (int i = tid; i < PP; i += 1024) {
                unsigned key = s_key[i];
                if ((key & pmask) == prefix) s_f = key;
            }
            __syncthreads();
            fstar = s_f; resolved = true;
        }
    }

    // Round 2 (bits 7..0) + rare exact-tie round on index.
    if (!resolved) {
        scan_hist<8>(s_key, s_hist[0], prefix, pmask, 0, tid, lane);
        __syncthreads();
        if (tid < 64) pick_bin(s_hist[0], 256, s_knext, lane, &s_chosen, &s_knext, &s_cnt);
        else { for (int k = tid - 64; k < HB; k += 960) s_hist[1][k] = 0; }
        __syncthreads();
        prefix |= (unsigned)s_chosen;
        fstar = prefix;
        if (s_knext < s_cnt) {         // kk-th lies inside a tied-value group
            int* hist = s_hist[1];     // cleared during round 2's pick
            for (int i = tid; i < PP; i += 1024) {
                bool active = (s_key[i] == fstar);
                unsigned bin = 4095u - (unsigned)i;    // desc index == asc rank
                unsigned long long mm = __ballot(active);
#pragma unroll
                for (int bit = 0; bit < 12; ++bit) {
                    unsigned long long bb = __ballot(active && ((bin >> bit) & 1));
                    mm &= ((bin >> bit) & 1) ? bb : ~bb;
                }
                if (active && (__ffsll((unsigned long long)mm) - 1 == lane))
                    atomicAdd(&hist[bin], (int)__popcll(mm));
            }
            __syncthreads();
            if (tid < 64) pick_bin(hist, HB, s_knext, lane, &s_chosen, &s_knext, &s_cnt);
            __syncthreads();
            ptie = 4095 - s_chosen;    // select ties with p <= ptie (smaller index first)
        }
    }

    // ---- Phase 4+5: one per-cell pass: selection, loss_c, featuremap outputs.
    double my_c = 0.0;
    for (int cI = tid; cI < CELLS; cI += 1024) {
        int mc = 0, hv = 0;
#pragma unroll
        for (int a = 0; a < 9; ++a) {
            int p = cI * 9 + a;
            int cv = s_ct[p];
            unsigned v = s_key[p];
            bool sel = (cv > 0) || (v > fstar) || (v == fstar && p <= ptie);
            mc = (cv > mc) ? cv : mc;
            hv |= sel ? 1 : 0;
            if (sel) my_c += (double)s_bov[p];
        }
        out[2 + (size_t)b * CELLS + cI] = (float)mc;
        out[2 + (size_t)BB * CELLS + (size_t)b * CELLS + cI] = (float)hv;
    }

#pragma unroll
    for (int off = 32; off > 0; off >>= 1) my_c += __shfl_down(my_c, off);
    if (lane == 0) s_pc[wid] = my_c;
    __syncthreads();
    if (tid == 0) {
        double L = 0.0;
#pragma unroll
        for (int w2 = 0; w2 < 16; ++w2) L += s_pc[w2];
        lossc[b] = L;
    }
}

__global__ __launch_bounds__(256) void finalize_kernel(
    const int* __restrict__ numpos, const double* __restrict__ lossl,
    const double* __restrict__ lossc, float* __restrict__ out)
{
    __shared__ double s_l[256], s_c[256];
    __shared__ int s_n[256];
    int tid = threadIdx.x;
    s_n[tid] = numpos[tid];     // BB == 256 == blockDim
    s_l[tid] = lossl[tid];
    s_c[tid] = lossc[tid];
    __syncthreads();
    for (int s = 128; s > 0; s >>= 1) {
        if (tid < s) { s_n[tid] += s_n[tid + s]; s_l[tid] += s_l[tid + s]; s_c[tid] += s_c[tid + s]; }
        __syncthreads();
    }
    if (tid == 0) {
        double N = (double)s_n[0];
        out[0] = (float)(s_l[0] / N);
        out[1] = (float)(s_c[0] / N);
    }
}

extern "C" void kernel_launch(void* const* d_in, const int* in_sizes, int n_in,
                              void* d_out, int out_size, void* d_ws, size_t ws_size,
                              hipStream_t stream) {
    const float* loc     = (const float*)d_in[0];  // (B, P, 4)
    const float* conf    = (const float*)d_in[1];  // (B, P, 21)
    const float* priors  = (const float*)d_in[2];  // (P, 4)
    const float* targets = (const float*)d_in[3];  // (B, 12, 5)
    float* out = (float*)d_out;

    double* ws_lossl  = (double*)d_ws;             // BB doubles
    double* ws_lossc  = ws_lossl + BB;             // BB doubles
    int*    ws_numpos = (int*)(ws_lossc + BB);     // BB ints

    hipLaunchKernelGGL(fused_kernel, dim3(BB), dim3(1024), 0, stream,
                       loc, conf, priors, targets, ws_numpos, ws_lossl, ws_lossc, out);
    hipLaunchKernelGGL(finalize_kernel, dim3(1), dim3(256), 0, stream,
                       ws_numpos, ws_lossl, ws_lossc, out);
}